// Round 2
// baseline (27923.648 us; speedup 1.0000x reference)
//
#include <hip/hip_runtime.h>
#include <hip/hip_bf16.h>
#include <math.h>

typedef __attribute__((ext_vector_type(8))) short bf16x8;
typedef __attribute__((ext_vector_type(4))) float f32x4;

#define TT 1024
#define BB 128
#define II 256
#define SS 512
#define OUT_T 1025
#define OUT_BSTRIDE ((size_t)OUT_T * SS)   // 524800

// ---------- bf16 helpers ----------
static __device__ __forceinline__ unsigned short f2bf(float f) {
  union { float f; unsigned int u; } v; v.f = f;
  unsigned int r = v.u + 0x7fffu + ((v.u >> 16) & 1u);
  return (unsigned short)(r >> 16);
}
static __device__ __forceinline__ float bf2f(unsigned short h) {
  union { unsigned int u; float f; } v; v.u = ((unsigned int)h) << 16;
  return v.f;
}
static __device__ __forceinline__ bf16x8 pack8(const float* p) {
  float4 a = *(const float4*)p;
  float4 b = *(const float4*)(p + 4);
  bf16x8 r;
  r[0]=(short)f2bf(a.x); r[1]=(short)f2bf(a.y); r[2]=(short)f2bf(a.z); r[3]=(short)f2bf(a.w);
  r[4]=(short)f2bf(b.x); r[5]=(short)f2bf(b.y); r[6]=(short)f2bf(b.z); r[7]=(short)f2bf(b.w);
  return r;
}
// tanh(x) = (e^{2x}-1)/(e^{2x}+1), e^{2x} = 2^{2*log2e*x}; clamp avoids inf*0=NaN
static __device__ __forceinline__ float fast_tanh(float x) {
  float x2 = fminf(x * 2.8853900817779268f, 88.0f);
  float e = __builtin_amdgcn_exp2f(x2);
  return (e - 1.0f) * __builtin_amdgcn_rcpf(e + 1.0f);
}

// =====================================================================
// Phase 1: input projections -> proj[t][b][1536] bf16:
//   [0:512)=x@B0w^T+b0, [512:1024)=x@B1w^T+b1, [1024:1536)=sigmoid(x@Gw^T+gb)
// =====================================================================
__global__ __launch_bounds__(256) void proj_kernel(
    const float* __restrict__ x,
    const float* __restrict__ B0w, const float* __restrict__ B0b,
    const float* __restrict__ B1w, const float* __restrict__ B1b,
    const float* __restrict__ Gw,  const float* __restrict__ Gb,
    unsigned short* __restrict__ proj)
{
  __shared__ unsigned short Ab[64 * 40];
  __shared__ unsigned short Bb[64 * 40];
  int bid = blockIdx.x;
  int nb = bid % 24, mb = bid / 24;
  int m0 = mb * 64, n0 = nb * 64;
  const float* Wp; const float* bp; bool isgate = false;
  if (n0 < 512)       { Wp = B0w + (size_t)n0 * II;          bp = B0b + n0; }
  else if (n0 < 1024) { Wp = B1w + (size_t)(n0 - 512) * II;  bp = B1b + (n0 - 512); }
  else                { Wp = Gw  + (size_t)(n0 - 1024) * II; bp = Gb + (n0 - 1024); isgate = true; }

  int tid = threadIdx.x;
  int lane = tid & 63, wid = tid >> 6;
  int r = tid >> 2, c = tid & 3;
  int mt0 = (wid >> 1) * 2, nt0 = (wid & 1) * 2;

  f32x4 acc[2][2] = {};
  for (int k0 = 0; k0 < II; k0 += 32) {
    __syncthreads();
    *(bf16x8*)&Ab[r * 40 + c * 8] = pack8(x  + (size_t)(m0 + r) * II + k0 + c * 8);
    *(bf16x8*)&Bb[r * 40 + c * 8] = pack8(Wp + (size_t)r * II       + k0 + c * 8);
    __syncthreads();
    bf16x8 af[2], bf[2];
#pragma unroll
    for (int mi = 0; mi < 2; ++mi)
      af[mi] = *(const bf16x8*)&Ab[((mt0 + mi) * 16 + (lane & 15)) * 40 + 8 * (lane >> 4)];
#pragma unroll
    for (int ni = 0; ni < 2; ++ni)
      bf[ni] = *(const bf16x8*)&Bb[((nt0 + ni) * 16 + (lane & 15)) * 40 + 8 * (lane >> 4)];
#pragma unroll
    for (int mi = 0; mi < 2; ++mi)
#pragma unroll
      for (int ni = 0; ni < 2; ++ni)
        acc[mi][ni] = __builtin_amdgcn_mfma_f32_16x16x32_bf16(af[mi], bf[ni], acc[mi][ni], 0, 0, 0);
  }
#pragma unroll
  for (int mi = 0; mi < 2; ++mi)
#pragma unroll
    for (int ni = 0; ni < 2; ++ni)
#pragma unroll
      for (int q = 0; q < 4; ++q) {
        int m  = m0 + (mt0 + mi) * 16 + (lane >> 4) * 4 + q;
        int nl = (nt0 + ni) * 16 + (lane & 15);
        int b = m >> 10, t = m & 1023;                // m = b*T + t
        float v = acc[mi][ni][q] + bp[nl];
        if (isgate) v = 1.0f / (1.0f + expf(-v));
        proj[((size_t)t * BB + b) * 1536 + n0 + nl] = f2bf(v);
      }
}

// =====================================================================
// Phase 2: recurrence, NO cross-block communication.
// 8 blocks x 1024 threads (16 waves). Block owns 16 batch rows, all 512 cols.
// A0/A1 column-slices live in REGISTERS as MFMA B-fragments (256 VGPR/wave).
// State exchanged per step via double-buffered LDS + one raw s_barrier.
// =====================================================================
__global__ __launch_bounds__(1024, 4) void recur_kernel(
    const float* __restrict__ s0,
    const float* __restrict__ A0w, const float* __restrict__ A1w,
    const unsigned short* __restrict__ proj,
    const float* __restrict__ alpha_p, const int* __restrict__ z_p,
    float* __restrict__ out)
{
  __shared__ unsigned short Sbuf[2][16 * 520];

  int tid = threadIdx.x;
  int lane = tid & 63, wid = tid >> 6;      // 16 waves
  int b0 = blockIdx.x * 16;
  int lane15 = lane & 15, kslot = lane >> 4;
  int c_w = wid * 32;                        // this wave's 32 output cols
  int rowbase = kslot * 4;
  float alpha = *alpha_p; int z = *z_p;
  float om_a = 1.0f - alpha;

  // ---- load A0/A1 column-slices into registers as B-fragments ----
  // Bf[ct][kk] lane layout: elem j = A[col = c_w+ct*16+lane15][k = kk*32+kslot*8+j]
  bf16x8 Bf0[2][16], Bf1[2][16];
#pragma unroll
  for (int ct = 0; ct < 2; ++ct) {
    int colg = c_w + ct * 16 + lane15;
#pragma unroll
    for (int kk = 0; kk < 16; ++kk) {
      int k0 = kk * 32 + kslot * 8;
      Bf0[ct][kk] = pack8(A0w + (size_t)colg * SS + k0);
      Bf1[ct][kk] = pack8(A1w + (size_t)colg * SS + k0);
    }
  }

  // ---- init: state t=0 into LDS (bf16), out[:,0,:] = s0, sprev in regs ----
  {
    int row = tid >> 6, c8 = tid & 63;
    const float* sp = s0 + (size_t)(b0 + row) * SS + c8 * 8;
    *(bf16x8*)&Sbuf[0][row * 520 + c8 * 8] = pack8(sp);
    float4 v0 = *(const float4*)sp, v1 = *(const float4*)(sp + 4);
    float* op = out + (size_t)(b0 + row) * OUT_BSTRIDE + c8 * 8;
    *(float4*)op = v0; *(float4*)(op + 4) = v1;
  }
  float sprev[2][4];
#pragma unroll
  for (int ct = 0; ct < 2; ++ct)
#pragma unroll
    for (int q = 0; q < 4; ++q)
      sprev[ct][q] = s0[(size_t)(b0 + rowbase + q) * SS + c_w + ct * 16 + lane15];

  // per-q proj pointers (advance by one t-slice per step); channel/ct offsets
  // are small immediates folded into the load instructions.
  const unsigned short* pj[4];
#pragma unroll
  for (int q = 0; q < 4; ++q)
    pj[q] = proj + (size_t)(b0 + rowbase + q) * 1536 + c_w + lane15;

  __syncthreads();

  for (int t = 0; t < TT; ++t) {
    int cur = t & 1;

    // ---- issue proj loads early (raw ushorts; waits land at first use) ----
    unsigned short rb0[2][4], rb1[2][4], rg[2][4];
#pragma unroll
    for (int q = 0; q < 4; ++q)
#pragma unroll
      for (int ct = 0; ct < 2; ++ct) {
        rb0[ct][q] = pj[q][ct * 16];
        rb1[ct][q] = pj[q][ct * 16 + 512];
        rg [ct][q] = pj[q][ct * 16 + 1024];
      }

    // ---- MFMA: u = S @ A^T for 32 cols (2 tiles) x 2 matrices ----
    f32x4 acc0[2] = {}, acc1[2] = {};
    const unsigned short* sb = &Sbuf[cur][lane15 * 520 + kslot * 8];
#pragma unroll
    for (int kk = 0; kk < 16; ++kk) {
      bf16x8 af = *(const bf16x8*)(sb + kk * 32);
      acc0[0] = __builtin_amdgcn_mfma_f32_16x16x32_bf16(af, Bf0[0][kk], acc0[0], 0, 0, 0);
      acc0[1] = __builtin_amdgcn_mfma_f32_16x16x32_bf16(af, Bf0[1][kk], acc0[1], 0, 0, 0);
      acc1[0] = __builtin_amdgcn_mfma_f32_16x16x32_bf16(af, Bf1[0][kk], acc1[0], 0, 0, 0);
      acc1[1] = __builtin_amdgcn_mfma_f32_16x16x32_bf16(af, Bf1[1][kk], acc1[1], 0, 0, 0);
    }

    // ---- elementwise + state write (LDS, other buffer) + out store ----
    unsigned short* snl = &Sbuf[cur ^ 1][0];
    size_t outt = (size_t)(t + 1) * SS;
#pragma unroll
    for (int ct = 0; ct < 2; ++ct) {
      int colg = c_w + ct * 16 + lane15;
#pragma unroll
      for (int q = 0; q < 4; ++q) {
        float u0 = acc0[ct][q] + bf2f(rb0[ct][q]);
        float f0 = fast_tanh(u0);
        float f;
        if (z != 0) {
          float u1 = acc1[ct][q] + bf2f(rb1[ct][q]);
          float f1 = fast_tanh(u1);
          f = om_a * f0 + alpha * f1;
        } else {
          f = f0;
        }
        float g = bf2f(rg[ct][q]);
        float sn = g * f + (1.0f - g) * sprev[ct][q];
        sprev[ct][q] = sn;
        out[(size_t)(b0 + rowbase + q) * OUT_BSTRIDE + outt + colg] = sn;
        snl[(rowbase + q) * 520 + colg] = f2bf(sn);
      }
    }
#pragma unroll
    for (int q = 0; q < 4; ++q) pj[q] += (size_t)BB * 1536;

    // LDS writes visible to all waves; no vmcnt drain (out stores in flight)
    asm volatile("s_waitcnt lgkmcnt(0)\n\ts_barrier" ::: "memory");
  }
}

// =====================================================================
extern "C" void kernel_launch(void* const* d_in, const int* in_sizes, int n_in,
                              void* d_out, int out_size, void* d_ws, size_t ws_size,
                              hipStream_t stream) {
  const float* x   = (const float*)d_in[0];
  const float* s0  = (const float*)d_in[1];
  const float* A0w = (const float*)d_in[2];
  const float* B0w = (const float*)d_in[3];
  const float* B0b = (const float*)d_in[4];
  const float* A1w = (const float*)d_in[5];
  const float* B1w = (const float*)d_in[6];
  const float* B1b = (const float*)d_in[7];
  const float* Gw  = (const float*)d_in[8];
  const float* Gb  = (const float*)d_in[9];
  const float* alp = (const float*)d_in[10];
  const int*   zp  = (const int*)d_in[11];
  float* out = (float*)d_out;

  unsigned short* proj = (unsigned short*)d_ws;   // [1024][128][1536] bf16

  proj_kernel<<<dim3((131072 / 64) * (1536 / 64)), dim3(256), 0, stream>>>(
      x, B0w, B0b, B1w, B1b, Gw, Gb, proj);

  recur_kernel<<<dim3(8), dim3(1024), 0, stream>>>(
      s0, A0w, A1w, proj, alp, zp, out);
}

// Round 3
// 3025.878 us; speedup vs baseline: 9.2283x; 9.2283x over previous
//
#include <hip/hip_runtime.h>
#include <hip/hip_bf16.h>
#include <math.h>

typedef __attribute__((ext_vector_type(8))) short bf16x8;
typedef __attribute__((ext_vector_type(4))) float f32x4;
typedef __attribute__((ext_vector_type(4))) int i32x4;

#define TT 1024
#define BB 128
#define II 256
#define SS 512
#define OUT_T 1025
#define OUT_BSTRIDE ((size_t)OUT_T * SS)   // 524800

// ---------- bf16 helpers ----------
static __device__ __forceinline__ unsigned short f2bf(float f) {
  union { float f; unsigned int u; } v; v.f = f;
  unsigned int r = v.u + 0x7fffu + ((v.u >> 16) & 1u);
  return (unsigned short)(r >> 16);
}
static __device__ __forceinline__ float bf2f(unsigned short h) {
  union { unsigned int u; float f; } v; v.u = ((unsigned int)h) << 16;
  return v.f;
}
static __device__ __forceinline__ bf16x8 pack8(const float* p) {
  float4 a = *(const float4*)p;
  float4 b = *(const float4*)(p + 4);
  bf16x8 r;
  r[0]=(short)f2bf(a.x); r[1]=(short)f2bf(a.y); r[2]=(short)f2bf(a.z); r[3]=(short)f2bf(a.w);
  r[4]=(short)f2bf(b.x); r[5]=(short)f2bf(b.y); r[6]=(short)f2bf(b.z); r[7]=(short)f2bf(b.w);
  return r;
}
// tanh(x) = (e^{2x}-1)/(e^{2x}+1), e^{2x} = 2^{x*2*log2(e)}; clamp avoids inf/inf
static __device__ __forceinline__ float fast_tanh(float x) {
  float x2 = fminf(x * 2.8853900817779268f, 88.0f);
  float e = __builtin_amdgcn_exp2f(x2);
  return (e - 1.0f) * __builtin_amdgcn_rcpf(e + 1.0f);
}

// ---------- device-coherent (cross-XCD safe, LLC) ops ----------
static __device__ __forceinline__ i32x4 ld_coh_b128_issue(const void* p) {
  i32x4 r;
  asm volatile("global_load_dwordx4 %0, %1, off sc0 sc1" : "=v"(r) : "v"(p) : "memory");
  return r;
}
static __device__ __forceinline__ unsigned int ld_coh_b32(const void* p) {
  unsigned int r;
  asm volatile("global_load_dword %0, %1, off sc0 sc1\n\ts_waitcnt vmcnt(0)"
               : "=v"(r) : "v"(p) : "memory");
  return r;
}
static __device__ __forceinline__ void st_coh_b128(void* p, i32x4 v) {
  asm volatile("global_store_dwordx4 %0, %1, off sc0 sc1" :: "v"(p), "v"(v) : "memory");
}
static __device__ __forceinline__ void st_coh_b32(void* p, unsigned int v) {
  asm volatile("global_store_dword %0, %1, off sc0 sc1" :: "v"(p), "v"(v) : "memory");
}
static __device__ __forceinline__ void waitcnt_vm0() {
  asm volatile("s_waitcnt vmcnt(0)" ::: "memory");
}

// =====================================================================
// Phase 1: input projections -> proj[t][b][1536] bf16:
//   [0:512)=x@B0w^T+b0, [512:1024)=x@B1w^T+b1, [1024:1536)=sigmoid(x@Gw^T+gb)
// =====================================================================
__global__ __launch_bounds__(256) void proj_kernel(
    const float* __restrict__ x,
    const float* __restrict__ B0w, const float* __restrict__ B0b,
    const float* __restrict__ B1w, const float* __restrict__ B1b,
    const float* __restrict__ Gw,  const float* __restrict__ Gb,
    unsigned short* __restrict__ proj)
{
  __shared__ unsigned short Ab[64 * 40];
  __shared__ unsigned short Bb[64 * 40];
  int bid = blockIdx.x;
  int nb = bid % 24, mb = bid / 24;
  int m0 = mb * 64, n0 = nb * 64;
  const float* Wp; const float* bp; bool isgate = false;
  if (n0 < 512)       { Wp = B0w + (size_t)n0 * II;          bp = B0b + n0; }
  else if (n0 < 1024) { Wp = B1w + (size_t)(n0 - 512) * II;  bp = B1b + (n0 - 512); }
  else                { Wp = Gw  + (size_t)(n0 - 1024) * II; bp = Gb + (n0 - 1024); isgate = true; }

  int tid = threadIdx.x;
  int lane = tid & 63, wid = tid >> 6;
  int r = tid >> 2, c = tid & 3;
  int mt0 = (wid >> 1) * 2, nt0 = (wid & 1) * 2;

  f32x4 acc[2][2] = {};
  for (int k0 = 0; k0 < II; k0 += 32) {
    __syncthreads();
    *(bf16x8*)&Ab[r * 40 + c * 8] = pack8(x  + (size_t)(m0 + r) * II + k0 + c * 8);
    *(bf16x8*)&Bb[r * 40 + c * 8] = pack8(Wp + (size_t)r * II       + k0 + c * 8);
    __syncthreads();
    bf16x8 af[2], bf[2];
#pragma unroll
    for (int mi = 0; mi < 2; ++mi)
      af[mi] = *(const bf16x8*)&Ab[((mt0 + mi) * 16 + (lane & 15)) * 40 + 8 * (lane >> 4)];
#pragma unroll
    for (int ni = 0; ni < 2; ++ni)
      bf[ni] = *(const bf16x8*)&Bb[((nt0 + ni) * 16 + (lane & 15)) * 40 + 8 * (lane >> 4)];
#pragma unroll
    for (int mi = 0; mi < 2; ++mi)
#pragma unroll
      for (int ni = 0; ni < 2; ++ni)
        acc[mi][ni] = __builtin_amdgcn_mfma_f32_16x16x32_bf16(af[mi], bf[ni], acc[mi][ni], 0, 0, 0);
  }
#pragma unroll
  for (int mi = 0; mi < 2; ++mi)
#pragma unroll
    for (int ni = 0; ni < 2; ++ni)
#pragma unroll
      for (int q = 0; q < 4; ++q) {
        int m  = m0 + (mt0 + mi) * 16 + (lane >> 4) * 4 + q;
        int nl = (nt0 + ni) * 16 + (lane & 15);
        int b = m >> 10, t = m & 1023;                // m = b*T + t
        float v = acc[mi][ni][q] + bp[nl];
        if (isgate) v = 1.0f / (1.0f + expf(-v));
        proj[((size_t)t * BB + b) * 1536 + n0 + nl] = f2bf(v);
      }
}

// =====================================================================
// Phase 2: recurrence. 64 blocks = 8 batch-groups (g) x 8 col-slices (j).
// Block: 16 batch rows x 64 state cols, 256 threads (4 waves, 1 wave/SIMD).
// A0/A1 col-slice fragments RESIDENT IN REGISTERS (128 VGPR/lane).
// Per step: MFMA -> elementwise -> LDS-pack own slice -> 128x coherent
// dwordx4 stores -> drain -> flag; out stores + next proj loads overlap the
// peer-flag poll; peer slices loaded dwordx4 into LDS.
// =====================================================================
__global__ __launch_bounds__(256, 1) void recur_kernel(
    const float* __restrict__ s0,
    const float* __restrict__ A0w, const float* __restrict__ A1w,
    const unsigned short* __restrict__ proj,
    const float* __restrict__ alpha_p, const int* __restrict__ z_p,
    unsigned short* state_bf,          // [2][128][512] bf16 ping-pong
    unsigned int* flags,               // [8 groups][8 slices]
    float* __restrict__ out)           // [128][1025][512]
{
  __shared__ unsigned short Ss[16 * 520];   // current state tile [16 rows][512+pad]

  int tid = threadIdx.x, lane = tid & 63, wid = tid >> 6;   // 4 waves
  int g = blockIdx.x & 7, j = blockIdx.x >> 3;
  int b0 = g * 16, c0 = j * 64;
  int lane15 = lane & 15, kslot = lane >> 4;
  int rowbase = kslot * 4;
  int colw = c0 + wid * 16 + lane15;        // this lane's output col
  float alpha = *alpha_p; int z = *z_p;
  float om_a = 1.0f - alpha;

  // ---- A0/A1 column-slice B-fragments resident in registers ----
  // Af[kk] elem e = A[col=colw][k = kk*32 + kslot*8 + e]
  bf16x8 Af0[16], Af1[16];
#pragma unroll
  for (int kk = 0; kk < 16; ++kk) {
    int k0 = kk * 32 + kslot * 8;
    Af0[kk] = pack8(A0w + (size_t)colw * SS + k0);
    Af1[kk] = pack8(A1w + (size_t)colw * SS + k0);
  }

  // ---- prologue: Ss = s0 tile (bf16); out[:,0,:] (j==0 only); sprev regs ----
#pragma unroll
  for (int c2 = 0; c2 < 4; ++c2) {
    int e = tid + 256 * c2; int rr = e >> 6, kc = e & 63;
    *(bf16x8*)&Ss[rr * 520 + kc * 8] = pack8(s0 + (size_t)(b0 + rr) * SS + kc * 8);
  }
  if (j == 0) {
#pragma unroll
    for (int c2 = 0; c2 < 4; ++c2) {
      int e = tid + 256 * c2; int rr = e >> 6, kc = e & 63;
      const float* sp = s0 + (size_t)(b0 + rr) * SS + kc * 8;
      float* op = out + (size_t)(b0 + rr) * OUT_BSTRIDE + kc * 8;
      *(float4*)op = *(const float4*)sp;
      *(float4*)(op + 4) = *(const float4*)(sp + 4);
    }
  }
  float sprev[4];
#pragma unroll
  for (int q = 0; q < 4; ++q)
    sprev[q] = s0[(size_t)(b0 + rowbase + q) * SS + colw];

  // proj pointers + first-step proj values
  const unsigned short* pj[4];
  unsigned short pb0[4], pb1[4], pg[4];
#pragma unroll
  for (int q = 0; q < 4; ++q) {
    pj[q] = proj + (size_t)(b0 + rowbase + q) * 1536 + colw;
    pb0[q] = pj[q][0]; pb1[q] = pj[q][512]; pg[q] = pj[q][1024];
  }

  __syncthreads();

  for (int t = 0; t < TT; ++t) {
    // ---- MFMA: u = s_t @ A^T, this wave's 16 cols, both matrices ----
    f32x4 acc0 = {0.f,0.f,0.f,0.f}, acc1 = {0.f,0.f,0.f,0.f};
    const unsigned short* sb = &Ss[lane15 * 520 + kslot * 8];
#pragma unroll
    for (int kk = 0; kk < 16; ++kk) {
      bf16x8 af = *(const bf16x8*)(sb + kk * 32);
      acc0 = __builtin_amdgcn_mfma_f32_16x16x32_bf16(af, Af0[kk], acc0, 0, 0, 0);
      acc1 = __builtin_amdgcn_mfma_f32_16x16x32_bf16(af, Af1[kk], acc1, 0, 0, 0);
    }
    __syncthreads();   // B1: all waves done reading Ss (s_t)

    // ---- elementwise; write own next-state into Ss (bf16) ----
    float sn[4];
#pragma unroll
    for (int q = 0; q < 4; ++q) {
      float f0 = fast_tanh(acc0[q] + bf2f(pb0[q]));
      float f;
      if (z != 0) {
        float f1 = fast_tanh(acc1[q] + bf2f(pb1[q]));
        f = om_a * f0 + alpha * f1;
      } else {
        f = f0;
      }
      float gg = bf2f(pg[q]);
      sn[q] = gg * f + (1.0f - gg) * sprev[q];
      sprev[q] = sn[q];
      Ss[(rowbase + q) * 520 + colw] = f2bf(sn[q]);
    }
    __syncthreads();   // B2: own 16x64 region of s_{t+1} complete in Ss

    // ---- packed coherent store of own slice (2KB = 128 x dwordx4) ----
    unsigned short* snext = state_bf + (size_t)((t + 1) & 1) * BB * SS;
    if (tid < 128) {
      int row = tid >> 3, ch = tid & 7;
      i32x4 v = *(const i32x4*)&Ss[row * 520 + c0 + ch * 8];
      st_coh_b128(snext + (size_t)(b0 + row) * SS + c0 + ch * 8, v);
      waitcnt_vm0();
    }
    __syncthreads();   // B3: slice at coherence point
    if (tid == 0) st_coh_b32(flags + g * 8 + j, (unsigned int)(t + 1));

    // ---- overlap window: out stores (HBM) + next-step proj loads ----
#pragma unroll
    for (int q = 0; q < 4; ++q)
      out[(size_t)(b0 + rowbase + q) * OUT_BSTRIDE + (size_t)(t + 1) * SS + colw] = sn[q];
    if (t + 1 < TT) {
#pragma unroll
      for (int q = 0; q < 4; ++q) {
        pj[q] += (size_t)BB * 1536;
        pb0[q] = pj[q][0]; pb1[q] = pj[q][512]; pg[q] = pj[q][1024];
      }
      // ---- poll peer flags, then load full 16x512 s_{t+1} into Ss ----
      if (wid == 0 && lane < 8) {
        const unsigned int* fp = flags + g * 8 + lane;
        while (ld_coh_b32(fp) < (unsigned int)(t + 1)) {}
      }
      __syncthreads(); // B4: all 8 slices of s_{t+1} visible
      i32x4 v[4];
#pragma unroll
      for (int c2 = 0; c2 < 4; ++c2) {
        int e = tid + 256 * c2; int rr = e >> 6, kc = e & 63;
        v[c2] = ld_coh_b128_issue(snext + (size_t)(b0 + rr) * SS + kc * 8);
      }
      waitcnt_vm0();
#pragma unroll
      for (int c2 = 0; c2 < 4; ++c2) {
        int e = tid + 256 * c2; int rr = e >> 6, kc = e & 63;
        *(bf16x8*)&Ss[rr * 520 + kc * 8] = *(bf16x8*)&v[c2];
      }
      __syncthreads(); // B5: Ss holds s_{t+1}
    }
  }
}

// =====================================================================
extern "C" void kernel_launch(void* const* d_in, const int* in_sizes, int n_in,
                              void* d_out, int out_size, void* d_ws, size_t ws_size,
                              hipStream_t stream) {
  const float* x   = (const float*)d_in[0];
  const float* s0  = (const float*)d_in[1];
  const float* A0w = (const float*)d_in[2];
  const float* B0w = (const float*)d_in[3];
  const float* B0b = (const float*)d_in[4];
  const float* A1w = (const float*)d_in[5];
  const float* B1w = (const float*)d_in[6];
  const float* B1b = (const float*)d_in[7];
  const float* Gw  = (const float*)d_in[8];
  const float* Gb  = (const float*)d_in[9];
  const float* alp = (const float*)d_in[10];
  const int*   zp  = (const int*)d_in[11];
  float* out = (float*)d_out;

  char* ws = (char*)d_ws;
  size_t proj_bytes  = (size_t)BB * TT * 1536 * 2;        // 402,653,184
  size_t state_off   = proj_bytes;
  size_t state_bytes = (size_t)2 * BB * SS * 2;           // 262,144
  size_t flag_off    = state_off + state_bytes;
  unsigned short* proj     = (unsigned short*)(ws);
  unsigned short* state_bf = (unsigned short*)(ws + state_off);
  unsigned int*   flags    = (unsigned int*)(ws + flag_off);

  hipMemsetAsync(flags, 0, 64 * sizeof(unsigned int), stream);

  proj_kernel<<<dim3((131072 / 64) * (1536 / 64)), dim3(256), 0, stream>>>(
      x, B0w, B0b, B1w, B1b, Gw, Gb, proj);

  recur_kernel<<<dim3(64), dim3(256), 0, stream>>>(
      s0, A0w, A1w, proj, alp, zp, state_bf, flags, out);
}